// Round 7
// baseline (1148.781 us; speedup 1.0000x reference)
//
#include <hip/hip_runtime.h>
#include <hip/hip_bf16.h>

// Problem constants (R=4096, S=128, V=3, F=35)
#define NPTS      524288            // R*S
#define OUT2_BASE 4718592           // NPTS*9  (rgb_in elements)
#define NBLK64    8192              // NPTS/64

using bf16x8 = __attribute__((ext_vector_type(8))) short;   // MFMA A/B frag
using f32x4  = __attribute__((ext_vector_type(4))) float;   // MFMA C/D frag

#define MFMA(a, b, c) __builtin_amdgcn_mfma_f32_16x16x32_bf16(a, b, c, 0, 0, 0)

// Weight workspace (ushort/bf16 in d_ws), [N][K] row-major, K padded, pads ZEROED:
//   WG [64][96]  @ 0      = bw1 mean part at cols 0..34, VAR part at cols 40..74
//   WF [64][72]  @ 6144   = bw1[:, 70:105](view part),  cols 35..71 = 0
//   W2 [32][72]  @ 10752  = bw2,  cols 64..71 = 0
//   V1 [32][40]  @ 13056  = vw1/3 (x/num_views folded), cols 32..39 = 0
//   V2 [32][40]  @ 14336  = vw2,  cols 32..39 = 0
//   R1 [32][104] @ 15616  = rw1,  cols 96..103 = 0
//   R2 [16][40]  @ 18944  = rw2,  cols 32..39 = 0

__device__ __forceinline__ ushort f2bf(float f) {
    union { float f; unsigned u; } v; v.f = f;
    unsigned u = v.u;
    unsigned r = u + 0x7fffu + ((u >> 16) & 1u);   // RTNE
    return (ushort)(r >> 16);
}
__device__ __forceinline__ uint pack2(float a, float b) {   // lo=bf16(a), hi=bf16(b)
    union { __hip_bfloat162 h; uint u; } cv;
    cv.h = __float22bfloat162_rn(make_float2(a, b));
    return cv.u;
}
__device__ __forceinline__ float eluf(float x) {
    return fmaxf(x, 0.f) + __expf(fminf(x, 0.f)) - 1.f;
}
__device__ __forceinline__ float sigm(float x) { return 1.f / (1.f + __expf(-x)); }

__device__ __forceinline__ void load8(const float* __restrict__ p, float* d) {
    __builtin_memcpy(d, p, 16);
    __builtin_memcpy(d + 4, p + 4, 16);
}
__device__ __forceinline__ bf16x8 pk8(const float* x) {     // 8 f32 -> bf16x8
    union { uint4 u; bf16x8 h; } cv;
    cv.u = make_uint4(pack2(x[0], x[1]), pack2(x[2], x[3]),
                      pack2(x[4], x[5]), pack2(x[6], x[7]));
    return cv.h;
}
__device__ __forceinline__ bf16x8 pk4u(uint a, uint b, uint c, uint d) {
    union { uint4 u; bf16x8 h; } cv;
    cv.u = make_uint4(a, b, c, d);
    return cv.h;
}
__device__ __forceinline__ bf16x8 ldw(const ushort* p) { return *(const bf16x8*)p; }

__global__ void prep_k(const float* __restrict__ bw1, const float* __restrict__ bw2,
                       const float* __restrict__ vw1, const float* __restrict__ vw2,
                       const float* __restrict__ rw1, const float* __restrict__ rw2,
                       ushort* __restrict__ w)
{
    int i = blockIdx.x * 256 + threadIdx.x;
    if (i < 6144) {                                   // WG [64][96] mean@0..34, var@40..74
        int n = i / 96, k = i % 96;
        float val = 0.f;
        if (k < 35)                 val = bw1[n * 105 + k];
        else if (k >= 40 && k < 75) val = bw1[n * 105 + 35 + (k - 40)];
        w[i] = f2bf(val);
    } else if (i < 10752) {                           // WF [64][72]
        int t = i - 6144, n = t / 72, k = t % 72;
        w[i] = f2bf(k < 35 ? bw1[n * 105 + 70 + k] : 0.f);
    } else if (i < 13056) {                           // W2 [32][72]
        int t = i - 10752, n = t / 72, k = t % 72;
        w[i] = f2bf(k < 64 ? bw2[n * 64 + k] : 0.f);
    } else if (i < 14336) {                           // V1 [32][40] (/3 folded)
        int t = i - 13056, n = t / 40, k = t % 40;
        w[i] = f2bf(k < 32 ? vw1[n * 32 + k] * (1.f / 3.f) : 0.f);
    } else if (i < 15616) {                           // V2 [32][40]
        int t = i - 14336, n = t / 40, k = t % 40;
        w[i] = f2bf(k < 32 ? vw2[n * 32 + k] : 0.f);
    } else if (i < 18944) {                           // R1 [32][104]
        int t = i - 15616, n = t / 104, k = t % 104;
        w[i] = f2bf(k < 96 ? rw1[n * 96 + k] : 0.f);
    } else if (i < 19584) {                           // R2 [16][40]
        int t = i - 18944, n = t / 40, k = t % 40;
        w[i] = f2bf(k < 32 ? rw2[n * 32 + k] : 0.f);
    }
}

// WAVE-INDEPENDENT, ZERO-barrier, OCCUPANCY-MAXED kernel.
// 4 waves/block (256 thr), each wave owns 16 points end-to-end; 8192 blocks.
// PER-VIEW pipeline (the occupancy lever vs R6): layer2 / vis1 / vis2 are
// per-view independent and r1's K=96 splits by view -> process
// h1_v -> h2_v -> t1_v -> x2_v -> CR += R1_v @ x2_v   for v = 0,1,2,
// so live LDS is only h1_v (2 KB) + one 1.25 KB ping buffer: 3328 B/wave,
// 13312 B/block (was 36864) -> LDS allows 8 blocks/CU; launch_bounds(256,8)
// forces VGPR<=64 -> up to 32 waves/CU (was 16). Waves slide freely (no
// __syncthreads anywhere; wave-private LDS, per-wave in-order DS ops).
// TRANSPOSED-C: mfma(W,X) -> lane holds 4 consecutive feats of point n16.
// LDS rows padded to 80 B where rows were 64 B (kills the 4-way sw3 conflict).
// Per-wave LDS: B1 2048 B (h1_v [16][128B] -> x2_v [16][80B] -> r2b [16][80B])
//               B2 1280 B (h2_v -> t1_v -> r1 [16][80B])
__global__ __launch_bounds__(256, 8) void mlp_k(
    const float* __restrict__ feat, const ushort* __restrict__ w,
    const float* __restrict__ bb1, const float* __restrict__ bb2,
    const float* __restrict__ vb1, const float* __restrict__ vb2,
    const float* __restrict__ rb1, const float* __restrict__ rb2,
    const float* __restrict__ rw3, const float* __restrict__ rb3,
    float* __restrict__ out)
{
    __shared__ __align__(16) char sh[4][3328];        // 13312 B / block

    const int tid  = threadIdx.x;
    const int wave = tid >> 6;
    const int lane = tid & 63;
    const int n16  = lane & 15;         // point within wave tile
    const int quad = lane >> 4;         // k-chunk / feature-quad
    char* const B1 = sh[wave];          // 2048 B
    char* const B2 = sh[wave] + 2048;   // 1280 B
    const int sw7 = n16 & 7;            // swizzle for 128B rows (8 slots)
    const int sw3 = n16 & 3;            // swizzle for 80B rows (4 slots)

    const long long pbase = (long long)blockIdx.x * 64 + wave * 16;
    const long long pt    = pbase + n16;
    const float* row = feat + pt * 105;

    const ushort* WG = w;
    const ushort* WF = w + 6144;
    const ushort* W2 = w + 10752;
    const ushort* V1 = w + 13056;
    const ushort* V2 = w + 14336;
    const ushort* R1 = w + 15616;
    const ushort* R2 = w + 18944;

    // ---- rgb_in passthrough (fp32 exact): 16 pts x 9 per wave, coalesced store ----
    {
        float* o1 = out + pbase * 9;
        const float* f0 = feat + pbase * 105;
#pragma unroll
        for (int t = 0; t < 3; ++t) {
            int i = lane + t * 64;
            if (t < 2 || lane < 16) {
                int p = i / 9, r = i - p * 9, v = r / 3, c = r - v * 3;
                o1[i] = f0[p * 105 + v * 35 + c];
            }
        }
    }

    // ---- build X in registers (R6-validated): lane loads its own B-frag floats ----
    float A0[8], A1[8], A2[8];
    load8(row + 8 * quad,      A0);     // view 0, feats 8q..8q+7
    load8(row + 35 + 8 * quad, A1);     // view 1
    load8(row + 70 + 8 * quad, A2);     // view 2 (max idx 101 < 105)
    float E0[8] = {0,0,0,0,0,0,0,0}, E1[8] = {0,0,0,0,0,0,0,0}, E2[8] = {0,0,0,0,0,0,0,0};
    if (quad == 0) {                    // feats 32..39 (35..39 garbage x zero weight)
        load8(row + 32, E0);
        load8(row + 67, E1);
        if (pt == (long long)NPTS - 1) {   // guard: row+102+7 runs off the array
            E2[0] = row[102]; E2[1] = row[103]; E2[2] = row[104];
        } else {
            load8(row + 102, E2);
        }
    }
    float M[8], Vv[8], M4[8], V4[8];
#pragma unroll
    for (int j = 0; j < 8; ++j) {
        float a = A0[j], b = A1[j], c = A2[j];
        float m = (a + b + c) * (1.f / 3.f);
        float da = a - m, db = b - m, dc = c - m;
        M[j] = m; Vv[j] = (da * da + db * db + dc * dc) * (1.f / 3.f);
        float a4 = E0[j], b4 = E1[j], c4 = E2[j];
        float m4 = (a4 + b4 + c4) * (1.f / 3.f);
        float e4 = a4 - m4, f4 = b4 - m4, g4 = c4 - m4;
        M4[j] = m4; V4[j] = (e4 * e4 + f4 * f4 + g4 * g4) * (1.f / 3.f);
    }
    uint vPK[4], v4PK[4], m4PK[4];
#pragma unroll
    for (int i = 0; i < 4; ++i) {
        vPK[i]  = pack2(Vv[2 * i], Vv[2 * i + 1]);
        v4PK[i] = pack2(V4[2 * i], V4[2 * i + 1]);
        m4PK[i] = pack2(M4[2 * i], M4[2 * i + 1]);
    }
    bf16x8 XAv[3], XBv[3];
    XAv[0] = pk8(A0); XAv[1] = pk8(A1); XAv[2] = pk8(A2);
    const bf16x8 ZF = pk4u(0u, 0u, 0u, 0u);
    XBv[0] = ZF; XBv[1] = ZF; XBv[2] = ZF;
    if (quad == 0) { XBv[0] = pk8(E0); XBv[1] = pk8(E1); XBv[2] = pk8(E2); }
    const bf16x8 G0 = pk8(M);
    const int prevAddr = ((lane + 48) & 63) * 4;   // cyclic previous quad, same n16
    uint G1u[4], G2u[4];
#pragma unroll
    for (int i = 0; i < 4; ++i) {
        uint bv  = (uint)__builtin_amdgcn_ds_bpermute(prevAddr, (int)vPK[i]);
        uint bv4 = (uint)__builtin_amdgcn_ds_bpermute(prevAddr, (int)v4PK[i]);
        G1u[i] = (quad == 0) ? m4PK[i] : bv;
        G2u[i] = (quad == 0) ? bv : ((quad == 1) ? bv4 : 0u);
    }
    const bf16x8 G1 = pk4u(G1u[0], G1u[1], G1u[2], G1u[3]);
    const bf16x8 G2 = pk4u(G2u[0], G2u[1], G2u[2], G2u[3]);

    const f32x4 Z = {0.f, 0.f, 0.f, 0.f};

    // ---- Cg (global-feat part of layer 1), view-invariant: 12 MFMA, lives in regs ----
    f32x4 Cg[4];
#pragma unroll
    for (int ntl = 0; ntl < 4; ++ntl) {
        const ushort* WGb = WG + (ntl * 16 + n16) * 96 + quad * 8;
        f32x4 c = MFMA(ldw(WGb), G0, Z);
        c = MFMA(ldw(WGb + 32), G1, c);
        Cg[ntl] = MFMA(ldw(WGb + 64), G2, c);
    }

    // ---- per-view pipeline ----
    f32x4 CR[2] = {Z, Z};
#pragma unroll
    for (int v = 0; v < 3; ++v) {
        // layer 1 (view part folded onto Cg): h1_v -> B1 [16 rows][128 B], swz sw7
#pragma unroll
        for (int ntl = 0; ntl < 4; ++ntl) {
            const ushort* WFb = WF + (ntl * 16 + n16) * 72 + quad * 8;
            f32x4 C = MFMA(ldw(WFb), XAv[v], Cg[ntl]);
            C = MFMA(ldw(WFb + 32), XBv[v], C);
            const float4 bq = *(const float4*)(bb1 + ntl * 16 + quad * 4);
            float e0 = eluf(C[0] + bq.x), e1 = eluf(C[1] + bq.y);
            float e2 = eluf(C[2] + bq.z), e3 = eluf(C[3] + bq.w);
            uint2 u; u.x = pack2(e0, e1); u.y = pack2(e2, e3);
            int slot = (ntl * 2 + (quad >> 1)) ^ sw7;
            *(uint2*)(B1 + n16 * 128 + slot * 16 + (quad & 1) * 8) = u;
        }
        // layer 2: K=64 over h1_v -> h2_v in B2 [16][80 B], swz sw3
        const bf16x8 ha = *(const bf16x8*)(B1 + n16 * 128 + ((quad ^ sw7) * 16));
        const bf16x8 hb = *(const bf16x8*)(B1 + n16 * 128 + (((4 + quad) ^ sw7) * 16));
        float h2r[2][4];
#pragma unroll
        for (int n2 = 0; n2 < 2; ++n2) {
            const ushort* W2b = W2 + (n2 * 16 + n16) * 72 + quad * 8;
            f32x4 C = MFMA(ldw(W2b), ha, Z);
            C = MFMA(ldw(W2b + 32), hb, C);
            const float4 bq = *(const float4*)(bb2 + n2 * 16 + quad * 4);
            float e0 = eluf(C[0] + bq.x), e1 = eluf(C[1] + bq.y);
            float e2 = eluf(C[2] + bq.z), e3 = eluf(C[3] + bq.w);
            h2r[n2][0] = e0; h2r[n2][1] = e1; h2r[n2][2] = e2; h2r[n2][3] = e3;
            uint2 u; u.x = pack2(e0, e1); u.y = pack2(e2, e3);
            int slot = (n2 * 2 + (quad >> 1)) ^ sw3;
            *(uint2*)(B2 + n16 * 80 + slot * 16 + (quad & 1) * 8) = u;
        }
        // vis layer 1: t1_v = elu(V1 @ h2_v) -> overwrite B2 (read precedes writes)
        {
            const bf16x8 hf = *(const bf16x8*)(B2 + n16 * 80 + ((quad ^ sw3) * 16));
#pragma unroll
            for (int n2 = 0; n2 < 2; ++n2) {
                f32x4 C = MFMA(ldw(V1 + (n2 * 16 + n16) * 40 + quad * 8), hf, Z);
                const float4 bq = *(const float4*)(vb1 + n2 * 16 + quad * 4);
                float e0 = eluf(C[0] + bq.x), e1 = eluf(C[1] + bq.y);
                float e2 = eluf(C[2] + bq.z), e3 = eluf(C[3] + bq.w);
                uint2 u; u.x = pack2(e0, e1); u.y = pack2(e2, e3);
                int slot = (n2 * 2 + (quad >> 1)) ^ sw3;
                *(uint2*)(B2 + n16 * 80 + slot * 16 + (quad & 1) * 8) = u;
            }
        }
        // vis layer 2 + residual: x2_v = h2_v + elu(V2 @ t1_v) -> B1 [16][80 B]
        {
            const bf16x8 tf = *(const bf16x8*)(B2 + n16 * 80 + ((quad ^ sw3) * 16));
#pragma unroll
            for (int n2 = 0; n2 < 2; ++n2) {
                f32x4 C = MFMA(ldw(V2 + (n2 * 16 + n16) * 40 + quad * 8), tf, Z);
                const float4 bq = *(const float4*)(vb2 + n2 * 16 + quad * 4);
                float x0 = h2r[n2][0] + eluf(C[0] + bq.x);
                float x1 = h2r[n2][1] + eluf(C[1] + bq.y);
                float x2v = h2r[n2][2] + eluf(C[2] + bq.z);
                float x3 = h2r[n2][3] + eluf(C[3] + bq.w);
                uint2 u; u.x = pack2(x0, x1); u.y = pack2(x2v, x3);
                int slot = (n2 * 2 + (quad >> 1)) ^ sw3;
                *(uint2*)(B1 + n16 * 80 + slot * 16 + (quad & 1) * 8) = u;
            }
        }
        // r1 accumulation: CR += R1[:, 32v..32v+31] @ x2_v
        {
            const bf16x8 xf = *(const bf16x8*)(B1 + n16 * 80 + ((quad ^ sw3) * 16));
#pragma unroll
            for (int n2 = 0; n2 < 2; ++n2)
                CR[n2] = MFMA(ldw(R1 + (n2 * 16 + n16) * 104 + v * 32 + quad * 8), xf, CR[n2]);
        }
    }

    // ---- r1 epilogue -> B2 ----
#pragma unroll
    for (int n2 = 0; n2 < 2; ++n2) {
        const float4 bq = *(const float4*)(rb1 + n2 * 16 + quad * 4);
        float e0 = eluf(CR[n2][0] + bq.x), e1 = eluf(CR[n2][1] + bq.y);
        float e2 = eluf(CR[n2][2] + bq.z), e3 = eluf(CR[n2][3] + bq.w);
        uint2 u; u.x = pack2(e0, e1); u.y = pack2(e2, e3);
        int slot = (n2 * 2 + (quad >> 1)) ^ sw3;
        *(uint2*)(B2 + n16 * 80 + slot * 16 + (quad & 1) * 8) = u;
    }

    // ---- r2 = elu(R2 @ r1) -> fp32 B1 [16][80 B] ----
    {
        const bf16x8 rf = *(const bf16x8*)(B2 + n16 * 80 + ((quad ^ sw3) * 16));
        f32x4 C3 = MFMA(ldw(R2 + n16 * 40 + quad * 8), rf, Z);
        const float4 bq2 = *(const float4*)(rb2 + quad * 4);
        float4 rv;
        rv.x = eluf(C3[0] + bq2.x);
        rv.y = eluf(C3[1] + bq2.y);
        rv.z = eluf(C3[2] + bq2.z);
        rv.w = eluf(C3[3] + bq2.w);
        *(float4*)(B1 + n16 * 80 + quad * 16) = rv;
    }

    // ---- final 16 -> 3 + sigmoid, coalesced 192-B store per wave ----
    if (lane < 48) {
        int p = lane / 3, c = lane - p * 3;
        const float4* rr = (const float4*)(B1 + p * 80);
        const float4* w3 = (const float4*)(rw3 + c * 16);
        float4 a0 = rr[0], a1 = rr[1], a2 = rr[2], a3 = rr[3];
        float4 q0 = w3[0], q1 = w3[1], q2 = w3[2], q3 = w3[3];
        float s = rb3[c];
        s += a0.x * q0.x + a0.y * q0.y + a0.z * q0.z + a0.w * q0.w;
        s += a1.x * q1.x + a1.y * q1.y + a1.z * q1.z + a1.w * q1.w;
        s += a2.x * q2.x + a2.y * q2.y + a2.z * q2.z + a2.w * q2.w;
        s += a3.x * q3.x + a3.y * q3.y + a3.z * q3.z + a3.w * q3.w;
        out[OUT2_BASE + pbase * 3 + lane] = sigm(s);
    }
}

extern "C" void kernel_launch(void* const* d_in, const int* in_sizes, int n_in,
                              void* d_out, int out_size, void* d_ws, size_t ws_size,
                              hipStream_t stream) {
    const float* feat = (const float*)d_in[0];
    const float* bw1  = (const float*)d_in[1];
    const float* bb1  = (const float*)d_in[2];
    const float* bw2  = (const float*)d_in[3];
    const float* bb2  = (const float*)d_in[4];
    const float* vw1  = (const float*)d_in[5];
    const float* vb1  = (const float*)d_in[6];
    const float* vw2  = (const float*)d_in[7];
    const float* vb2  = (const float*)d_in[8];
    const float* rw1  = (const float*)d_in[9];
    const float* rb1  = (const float*)d_in[10];
    const float* rw2  = (const float*)d_in[11];
    const float* rb2  = (const float*)d_in[12];
    const float* rw3  = (const float*)d_in[13];
    const float* rb3  = (const float*)d_in[14];
    ushort* w  = (ushort*)d_ws;
    float* out = (float*)d_out;

    hipLaunchKernelGGL(prep_k, dim3(77), dim3(256), 0, stream,
                       bw1, bw2, vw1, vw2, rw1, rw2, w);
    hipLaunchKernelGGL(mlp_k, dim3(NBLK64), dim3(256), 0, stream,
                       feat, w, bb1, bb2, vb1, vb2, rb1, rb2, rw3, rb3, out);
}

// Round 8
// 617.828 us; speedup vs baseline: 1.8594x; 1.8594x over previous
//
#include <hip/hip_runtime.h>
#include <hip/hip_bf16.h>

// Problem constants (R=4096, S=128, V=3, F=35)
#define NPTS      524288            // R*S
#define OUT2_BASE 4718592           // NPTS*9  (rgb_in elements)
#define NBLK64    8192              // NPTS/64

using bf16x8 = __attribute__((ext_vector_type(8))) short;   // MFMA A/B frag
using f32x4  = __attribute__((ext_vector_type(4))) float;   // MFMA C/D frag

#define MFMA(a, b, c) __builtin_amdgcn_mfma_f32_16x16x32_bf16(a, b, c, 0, 0, 0)

// Weight workspace (ushort/bf16 in d_ws), [N][K] row-major, K padded, pads ZEROED:
//   WG [64][96]  @ 0      = bw1 mean part at cols 0..34, VAR part at cols 40..74
//   WF [64][72]  @ 6144   = bw1[:, 70:105](view part),  cols 35..71 = 0
//   W2 [32][72]  @ 10752  = bw2,  cols 64..71 = 0
//   V1 [32][40]  @ 13056  = vw1/3 (x/num_views folded), cols 32..39 = 0
//   V2 [32][40]  @ 14336  = vw2,  cols 32..39 = 0
//   R1 [32][104] @ 15616  = rw1,  cols 96..103 = 0
//   R2 [16][40]  @ 18944  = rw2,  cols 32..39 = 0

__device__ __forceinline__ ushort f2bf(float f) {
    union { float f; unsigned u; } v; v.f = f;
    unsigned u = v.u;
    unsigned r = u + 0x7fffu + ((u >> 16) & 1u);   // RTNE
    return (ushort)(r >> 16);
}
__device__ __forceinline__ uint pack2(float a, float b) {   // lo=bf16(a), hi=bf16(b)
    union { __hip_bfloat162 h; uint u; } cv;
    cv.h = __float22bfloat162_rn(make_float2(a, b));
    return cv.u;
}
__device__ __forceinline__ float eluf(float x) {
    return fmaxf(x, 0.f) + __expf(fminf(x, 0.f)) - 1.f;
}
__device__ __forceinline__ float sigm(float x) { return 1.f / (1.f + __expf(-x)); }

__device__ __forceinline__ void load8(const float* __restrict__ p, float* d) {
    __builtin_memcpy(d, p, 16);
    __builtin_memcpy(d + 4, p + 4, 16);
}
__device__ __forceinline__ bf16x8 pk8(const float* x) {     // 8 f32 -> bf16x8
    union { uint4 u; bf16x8 h; } cv;
    cv.u = make_uint4(pack2(x[0], x[1]), pack2(x[2], x[3]),
                      pack2(x[4], x[5]), pack2(x[6], x[7]));
    return cv.h;
}
__device__ __forceinline__ bf16x8 pk4u(uint a, uint b, uint c, uint d) {
    union { uint4 u; bf16x8 h; } cv;
    cv.u = make_uint4(a, b, c, d);
    return cv.h;
}
__device__ __forceinline__ bf16x8 ldw(const ushort* p) { return *(const bf16x8*)p; }

__global__ void prep_k(const float* __restrict__ bw1, const float* __restrict__ bw2,
                       const float* __restrict__ vw1, const float* __restrict__ vw2,
                       const float* __restrict__ rw1, const float* __restrict__ rw2,
                       ushort* __restrict__ w)
{
    int i = blockIdx.x * 256 + threadIdx.x;
    if (i < 6144) {                                   // WG [64][96] mean@0..34, var@40..74
        int n = i / 96, k = i % 96;
        float val = 0.f;
        if (k < 35)                 val = bw1[n * 105 + k];
        else if (k >= 40 && k < 75) val = bw1[n * 105 + 35 + (k - 40)];
        w[i] = f2bf(val);
    } else if (i < 10752) {                           // WF [64][72]
        int t = i - 6144, n = t / 72, k = t % 72;
        w[i] = f2bf(k < 35 ? bw1[n * 105 + 70 + k] : 0.f);
    } else if (i < 13056) {                           // W2 [32][72]
        int t = i - 10752, n = t / 72, k = t % 72;
        w[i] = f2bf(k < 64 ? bw2[n * 64 + k] : 0.f);
    } else if (i < 14336) {                           // V1 [32][40] (/3 folded)
        int t = i - 13056, n = t / 40, k = t % 40;
        w[i] = f2bf(k < 32 ? vw1[n * 32 + k] * (1.f / 3.f) : 0.f);
    } else if (i < 15616) {                           // V2 [32][40]
        int t = i - 14336, n = t / 40, k = t % 40;
        w[i] = f2bf(k < 32 ? vw2[n * 32 + k] : 0.f);
    } else if (i < 18944) {                           // R1 [32][104]
        int t = i - 15616, n = t / 104, k = t % 104;
        w[i] = f2bf(k < 96 ? rw1[n * 96 + k] : 0.f);
    } else if (i < 19584) {                           // R2 [16][40]
        int t = i - 18944, n = t / 40, k = t % 40;
        w[i] = f2bf(k < 32 ? rw2[n * 32 + k] : 0.f);
    }
}

// WAVE-INDEPENDENT, ZERO-barrier, small-LDS kernel (R7 structure).
// R8 change vs R7: __launch_bounds__(256,4) -- R7's (256,8) forced VGPR 64->32
// and spilled everything to scratch (FETCH 1.05 GB, WRITE 1.5 GB, 910 us).
// With the cap at 128 VGPR the per-view pipeline fits without spill; LDS
// 13312 B/block allows 12 blocks/CU, so residency is VGPR-bound at ~5-6
// waves/SIMD (20-24 waves/CU vs 16 in all previous non-spilled rounds).
// 4 waves/block, each wave owns 16 points end-to-end; 8192 blocks.
// PER-VIEW pipeline: h1_v -> h2_v -> t1_v -> x2_v -> CR += R1_v @ x2_v (v=0,1,2);
// live LDS = h1_v (2 KB) + 1.25 KB ping buffer = 3328 B/wave.
// TRANSPOSED-C: mfma(W,X) -> lane holds 4 consecutive feats of point n16.
// Per-wave LDS: B1 2048 B (h1_v [16][128B] -> x2_v [16][80B] -> r2b [16][80B])
//               B2 1280 B (h2_v -> t1_v -> r1 [16][80B])
__global__ __launch_bounds__(256, 4) void mlp_k(
    const float* __restrict__ feat, const ushort* __restrict__ w,
    const float* __restrict__ bb1, const float* __restrict__ bb2,
    const float* __restrict__ vb1, const float* __restrict__ vb2,
    const float* __restrict__ rb1, const float* __restrict__ rb2,
    const float* __restrict__ rw3, const float* __restrict__ rb3,
    float* __restrict__ out)
{
    __shared__ __align__(16) char sh[4][3328];        // 13312 B / block

    const int tid  = threadIdx.x;
    const int wave = tid >> 6;
    const int lane = tid & 63;
    const int n16  = lane & 15;         // point within wave tile
    const int quad = lane >> 4;         // k-chunk / feature-quad
    char* const B1 = sh[wave];          // 2048 B
    char* const B2 = sh[wave] + 2048;   // 1280 B
    const int sw7 = n16 & 7;            // swizzle for 128B rows (8 slots)
    const int sw3 = n16 & 3;            // swizzle for 80B rows (4 slots)

    const long long pbase = (long long)blockIdx.x * 64 + wave * 16;
    const long long pt    = pbase + n16;
    const float* row = feat + pt * 105;

    const ushort* WG = w;
    const ushort* WF = w + 6144;
    const ushort* W2 = w + 10752;
    const ushort* V1 = w + 13056;
    const ushort* V2 = w + 14336;
    const ushort* R1 = w + 15616;
    const ushort* R2 = w + 18944;

    // ---- rgb_in passthrough (fp32 exact): 16 pts x 9 per wave, coalesced store ----
    {
        float* o1 = out + pbase * 9;
        const float* f0 = feat + pbase * 105;
#pragma unroll
        for (int t = 0; t < 3; ++t) {
            int i = lane + t * 64;
            if (t < 2 || lane < 16) {
                int p = i / 9, r = i - p * 9, v = r / 3, c = r - v * 3;
                o1[i] = f0[p * 105 + v * 35 + c];
            }
        }
    }

    // ---- build X in registers (R6-validated): lane loads its own B-frag floats ----
    float A0[8], A1[8], A2[8];
    load8(row + 8 * quad,      A0);     // view 0, feats 8q..8q+7
    load8(row + 35 + 8 * quad, A1);     // view 1
    load8(row + 70 + 8 * quad, A2);     // view 2 (max idx 101 < 105)
    float E0[8] = {0,0,0,0,0,0,0,0}, E1[8] = {0,0,0,0,0,0,0,0}, E2[8] = {0,0,0,0,0,0,0,0};
    if (quad == 0) {                    // feats 32..39 (35..39 garbage x zero weight)
        load8(row + 32, E0);
        load8(row + 67, E1);
        if (pt == (long long)NPTS - 1) {   // guard: row+102+7 runs off the array
            E2[0] = row[102]; E2[1] = row[103]; E2[2] = row[104];
        } else {
            load8(row + 102, E2);
        }
    }
    float M[8], Vv[8], M4[8], V4[8];
#pragma unroll
    for (int j = 0; j < 8; ++j) {
        float a = A0[j], b = A1[j], c = A2[j];
        float m = (a + b + c) * (1.f / 3.f);
        float da = a - m, db = b - m, dc = c - m;
        M[j] = m; Vv[j] = (da * da + db * db + dc * dc) * (1.f / 3.f);
        float a4 = E0[j], b4 = E1[j], c4 = E2[j];
        float m4 = (a4 + b4 + c4) * (1.f / 3.f);
        float e4 = a4 - m4, f4 = b4 - m4, g4 = c4 - m4;
        M4[j] = m4; V4[j] = (e4 * e4 + f4 * f4 + g4 * g4) * (1.f / 3.f);
    }
    uint vPK[4], v4PK[4], m4PK[4];
#pragma unroll
    for (int i = 0; i < 4; ++i) {
        vPK[i]  = pack2(Vv[2 * i], Vv[2 * i + 1]);
        v4PK[i] = pack2(V4[2 * i], V4[2 * i + 1]);
        m4PK[i] = pack2(M4[2 * i], M4[2 * i + 1]);
    }
    bf16x8 XAv[3], XBv[3];
    XAv[0] = pk8(A0); XAv[1] = pk8(A1); XAv[2] = pk8(A2);
    const bf16x8 ZF = pk4u(0u, 0u, 0u, 0u);
    XBv[0] = ZF; XBv[1] = ZF; XBv[2] = ZF;
    if (quad == 0) { XBv[0] = pk8(E0); XBv[1] = pk8(E1); XBv[2] = pk8(E2); }
    const bf16x8 G0 = pk8(M);
    const int prevAddr = ((lane + 48) & 63) * 4;   // cyclic previous quad, same n16
    uint G1u[4], G2u[4];
#pragma unroll
    for (int i = 0; i < 4; ++i) {
        uint bv  = (uint)__builtin_amdgcn_ds_bpermute(prevAddr, (int)vPK[i]);
        uint bv4 = (uint)__builtin_amdgcn_ds_bpermute(prevAddr, (int)v4PK[i]);
        G1u[i] = (quad == 0) ? m4PK[i] : bv;
        G2u[i] = (quad == 0) ? bv : ((quad == 1) ? bv4 : 0u);
    }
    const bf16x8 G1 = pk4u(G1u[0], G1u[1], G1u[2], G1u[3]);
    const bf16x8 G2 = pk4u(G2u[0], G2u[1], G2u[2], G2u[3]);

    const f32x4 Z = {0.f, 0.f, 0.f, 0.f};

    // ---- Cg (global-feat part of layer 1), view-invariant: 12 MFMA, lives in regs ----
    f32x4 Cg[4];
#pragma unroll
    for (int ntl = 0; ntl < 4; ++ntl) {
        const ushort* WGb = WG + (ntl * 16 + n16) * 96 + quad * 8;
        f32x4 c = MFMA(ldw(WGb), G0, Z);
        c = MFMA(ldw(WGb + 32), G1, c);
        Cg[ntl] = MFMA(ldw(WGb + 64), G2, c);
    }

    // ---- per-view pipeline ----
    f32x4 CR[2] = {Z, Z};
#pragma unroll
    for (int v = 0; v < 3; ++v) {
        // layer 1 (view part folded onto Cg): h1_v -> B1 [16 rows][128 B], swz sw7
#pragma unroll
        for (int ntl = 0; ntl < 4; ++ntl) {
            const ushort* WFb = WF + (ntl * 16 + n16) * 72 + quad * 8;
            f32x4 C = MFMA(ldw(WFb), XAv[v], Cg[ntl]);
            C = MFMA(ldw(WFb + 32), XBv[v], C);
            const float4 bq = *(const float4*)(bb1 + ntl * 16 + quad * 4);
            float e0 = eluf(C[0] + bq.x), e1 = eluf(C[1] + bq.y);
            float e2 = eluf(C[2] + bq.z), e3 = eluf(C[3] + bq.w);
            uint2 u; u.x = pack2(e0, e1); u.y = pack2(e2, e3);
            int slot = (ntl * 2 + (quad >> 1)) ^ sw7;
            *(uint2*)(B1 + n16 * 128 + slot * 16 + (quad & 1) * 8) = u;
        }
        // layer 2: K=64 over h1_v -> h2_v in B2 [16][80 B], swz sw3
        const bf16x8 ha = *(const bf16x8*)(B1 + n16 * 128 + ((quad ^ sw7) * 16));
        const bf16x8 hb = *(const bf16x8*)(B1 + n16 * 128 + (((4 + quad) ^ sw7) * 16));
        float h2r[2][4];
#pragma unroll
        for (int n2 = 0; n2 < 2; ++n2) {
            const ushort* W2b = W2 + (n2 * 16 + n16) * 72 + quad * 8;
            f32x4 C = MFMA(ldw(W2b), ha, Z);
            C = MFMA(ldw(W2b + 32), hb, C);
            const float4 bq = *(const float4*)(bb2 + n2 * 16 + quad * 4);
            float e0 = eluf(C[0] + bq.x), e1 = eluf(C[1] + bq.y);
            float e2 = eluf(C[2] + bq.z), e3 = eluf(C[3] + bq.w);
            h2r[n2][0] = e0; h2r[n2][1] = e1; h2r[n2][2] = e2; h2r[n2][3] = e3;
            uint2 u; u.x = pack2(e0, e1); u.y = pack2(e2, e3);
            int slot = (n2 * 2 + (quad >> 1)) ^ sw3;
            *(uint2*)(B2 + n16 * 80 + slot * 16 + (quad & 1) * 8) = u;
        }
        // vis layer 1: t1_v = elu(V1 @ h2_v) -> overwrite B2 (read precedes writes)
        {
            const bf16x8 hf = *(const bf16x8*)(B2 + n16 * 80 + ((quad ^ sw3) * 16));
#pragma unroll
            for (int n2 = 0; n2 < 2; ++n2) {
                f32x4 C = MFMA(ldw(V1 + (n2 * 16 + n16) * 40 + quad * 8), hf, Z);
                const float4 bq = *(const float4*)(vb1 + n2 * 16 + quad * 4);
                float e0 = eluf(C[0] + bq.x), e1 = eluf(C[1] + bq.y);
                float e2 = eluf(C[2] + bq.z), e3 = eluf(C[3] + bq.w);
                uint2 u; u.x = pack2(e0, e1); u.y = pack2(e2, e3);
                int slot = (n2 * 2 + (quad >> 1)) ^ sw3;
                *(uint2*)(B2 + n16 * 80 + slot * 16 + (quad & 1) * 8) = u;
            }
        }
        // vis layer 2 + residual: x2_v = h2_v + elu(V2 @ t1_v) -> B1 [16][80 B]
        {
            const bf16x8 tf = *(const bf16x8*)(B2 + n16 * 80 + ((quad ^ sw3) * 16));
#pragma unroll
            for (int n2 = 0; n2 < 2; ++n2) {
                f32x4 C = MFMA(ldw(V2 + (n2 * 16 + n16) * 40 + quad * 8), tf, Z);
                const float4 bq = *(const float4*)(vb2 + n2 * 16 + quad * 4);
                float x0 = h2r[n2][0] + eluf(C[0] + bq.x);
                float x1 = h2r[n2][1] + eluf(C[1] + bq.y);
                float x2v = h2r[n2][2] + eluf(C[2] + bq.z);
                float x3 = h2r[n2][3] + eluf(C[3] + bq.w);
                uint2 u; u.x = pack2(x0, x1); u.y = pack2(x2v, x3);
                int slot = (n2 * 2 + (quad >> 1)) ^ sw3;
                *(uint2*)(B1 + n16 * 80 + slot * 16 + (quad & 1) * 8) = u;
            }
        }
        // r1 accumulation: CR += R1[:, 32v..32v+31] @ x2_v
        {
            const bf16x8 xf = *(const bf16x8*)(B1 + n16 * 80 + ((quad ^ sw3) * 16));
#pragma unroll
            for (int n2 = 0; n2 < 2; ++n2)
                CR[n2] = MFMA(ldw(R1 + (n2 * 16 + n16) * 104 + v * 32 + quad * 8), xf, CR[n2]);
        }
    }

    // ---- r1 epilogue -> B2 ----
#pragma unroll
    for (int n2 = 0; n2 < 2; ++n2) {
        const float4 bq = *(const float4*)(rb1 + n2 * 16 + quad * 4);
        float e0 = eluf(CR[n2][0] + bq.x), e1 = eluf(CR[n2][1] + bq.y);
        float e2 = eluf(CR[n2][2] + bq.z), e3 = eluf(CR[n2][3] + bq.w);
        uint2 u; u.x = pack2(e0, e1); u.y = pack2(e2, e3);
        int slot = (n2 * 2 + (quad >> 1)) ^ sw3;
        *(uint2*)(B2 + n16 * 80 + slot * 16 + (quad & 1) * 8) = u;
    }

    // ---- r2 = elu(R2 @ r1) -> fp32 B1 [16][80 B] ----
    {
        const bf16x8 rf = *(const bf16x8*)(B2 + n16 * 80 + ((quad ^ sw3) * 16));
        f32x4 C3 = MFMA(ldw(R2 + n16 * 40 + quad * 8), rf, Z);
        const float4 bq2 = *(const float4*)(rb2 + quad * 4);
        float4 rv;
        rv.x = eluf(C3[0] + bq2.x);
        rv.y = eluf(C3[1] + bq2.y);
        rv.z = eluf(C3[2] + bq2.z);
        rv.w = eluf(C3[3] + bq2.w);
        *(float4*)(B1 + n16 * 80 + quad * 16) = rv;
    }

    // ---- final 16 -> 3 + sigmoid, coalesced 192-B store per wave ----
    if (lane < 48) {
        int p = lane / 3, c = lane - p * 3;
        const float4* rr = (const float4*)(B1 + p * 80);
        const float4* w3 = (const float4*)(rw3 + c * 16);
        float4 a0 = rr[0], a1 = rr[1], a2 = rr[2], a3 = rr[3];
        float4 q0 = w3[0], q1 = w3[1], q2 = w3[2], q3 = w3[3];
        float s = rb3[c];
        s += a0.x * q0.x + a0.y * q0.y + a0.z * q0.z + a0.w * q0.w;
        s += a1.x * q1.x + a1.y * q1.y + a1.z * q1.z + a1.w * q1.w;
        s += a2.x * q2.x + a2.y * q2.y + a2.z * q2.z + a2.w * q2.w;
        s += a3.x * q3.x + a3.y * q3.y + a3.z * q3.z + a3.w * q3.w;
        out[OUT2_BASE + pbase * 3 + lane] = sigm(s);
    }
}

extern "C" void kernel_launch(void* const* d_in, const int* in_sizes, int n_in,
                              void* d_out, int out_size, void* d_ws, size_t ws_size,
                              hipStream_t stream) {
    const float* feat = (const float*)d_in[0];
    const float* bw1  = (const float*)d_in[1];
    const float* bb1  = (const float*)d_in[2];
    const float* bw2  = (const float*)d_in[3];
    const float* bb2  = (const float*)d_in[4];
    const float* vw1  = (const float*)d_in[5];
    const float* vb1  = (const float*)d_in[6];
    const float* vw2  = (const float*)d_in[7];
    const float* vb2  = (const float*)d_in[8];
    const float* rw1  = (const float*)d_in[9];
    const float* rb1  = (const float*)d_in[10];
    const float* rw2  = (const float*)d_in[11];
    const float* rb2  = (const float*)d_in[12];
    const float* rw3  = (const float*)d_in[13];
    const float* rb3  = (const float*)d_in[14];
    ushort* w  = (ushort*)d_ws;
    float* out = (float*)d_out;

    hipLaunchKernelGGL(prep_k, dim3(77), dim3(256), 0, stream,
                       bw1, bw2, vw1, vw2, rw1, rw2, w);
    hipLaunchKernelGGL(mlp_k, dim3(NBLK64), dim3(256), 0, stream,
                       feat, w, bb1, bb2, vb1, vb2, rb1, rb2, rw3, rb3, out);
}

// Round 9
// 492.532 us; speedup vs baseline: 2.3324x; 1.2544x over previous
//
#include <hip/hip_runtime.h>
#include <hip/hip_bf16.h>

// Problem constants (R=4096, S=128, V=3, F=35)
#define NPTS      524288            // R*S
#define OUT2_BASE 4718592           // NPTS*9  (rgb_in elements)
#define NBLK64    8192              // NPTS/64

using bf16x8 = __attribute__((ext_vector_type(8))) short;   // MFMA A/B frag
using f32x4  = __attribute__((ext_vector_type(4))) float;   // MFMA C/D frag

#define MFMA(a, b, c) __builtin_amdgcn_mfma_f32_16x16x32_bf16(a, b, c, 0, 0, 0)

// Weight workspace (ushort/bf16 in d_ws), [N][K] row-major, K padded, pads ZEROED:
//   WG [64][96]  @ 0      = bw1 mean part at cols 0..34, VAR part at cols 40..74
//   WF [64][72]  @ 6144   = bw1[:, 70:105](view part),  cols 35..71 = 0
//   W2 [32][72]  @ 10752  = bw2,  cols 64..71 = 0
//   V1 [32][40]  @ 13056  = vw1/3 (x/num_views folded), cols 32..39 = 0
//   V2 [32][40]  @ 14336  = vw2,  cols 32..39 = 0
//   R1 [32][104] @ 15616  = rw1,  cols 96..103 = 0
//   R2 [16][40]  @ 18944  = rw2,  cols 32..39 = 0

__device__ __forceinline__ ushort f2bf(float f) {
    union { float f; unsigned u; } v; v.f = f;
    unsigned u = v.u;
    unsigned r = u + 0x7fffu + ((u >> 16) & 1u);   // RTNE
    return (ushort)(r >> 16);
}
__device__ __forceinline__ uint pack2(float a, float b) {   // lo=bf16(a), hi=bf16(b)
    union { __hip_bfloat162 h; uint u; } cv;
    cv.h = __float22bfloat162_rn(make_float2(a, b));
    return cv.u;
}
__device__ __forceinline__ float eluf(float x) {
    return fmaxf(x, 0.f) + __expf(fminf(x, 0.f)) - 1.f;
}
__device__ __forceinline__ float sigm(float x) { return 1.f / (1.f + __expf(-x)); }

__device__ __forceinline__ void load8(const float* __restrict__ p, float* d) {
    __builtin_memcpy(d, p, 16);
    __builtin_memcpy(d + 4, p + 4, 16);
}
__device__ __forceinline__ bf16x8 pk8(const float* x) {     // 8 f32 -> bf16x8
    union { uint4 u; bf16x8 h; } cv;
    cv.u = make_uint4(pack2(x[0], x[1]), pack2(x[2], x[3]),
                      pack2(x[4], x[5]), pack2(x[6], x[7]));
    return cv.h;
}
__device__ __forceinline__ bf16x8 pk4u(uint a, uint b, uint c, uint d) {
    union { uint4 u; bf16x8 h; } cv;
    cv.u = make_uint4(a, b, c, d);
    return cv.h;
}
__device__ __forceinline__ bf16x8 ldw(const ushort* p) { return *(const bf16x8*)p; }

__global__ void prep_k(const float* __restrict__ bw1, const float* __restrict__ bw2,
                       const float* __restrict__ vw1, const float* __restrict__ vw2,
                       const float* __restrict__ rw1, const float* __restrict__ rw2,
                       ushort* __restrict__ w)
{
    int i = blockIdx.x * 256 + threadIdx.x;
    if (i < 6144) {                                   // WG [64][96] mean@0..34, var@40..74
        int n = i / 96, k = i % 96;
        float val = 0.f;
        if (k < 35)                 val = bw1[n * 105 + k];
        else if (k >= 40 && k < 75) val = bw1[n * 105 + 35 + (k - 40)];
        w[i] = f2bf(val);
    } else if (i < 10752) {                           // WF [64][72]
        int t = i - 6144, n = t / 72, k = t % 72;
        w[i] = f2bf(k < 35 ? bw1[n * 105 + 70 + k] : 0.f);
    } else if (i < 13056) {                           // W2 [32][72]
        int t = i - 10752, n = t / 72, k = t % 72;
        w[i] = f2bf(k < 64 ? bw2[n * 64 + k] : 0.f);
    } else if (i < 14336) {                           // V1 [32][40] (/3 folded)
        int t = i - 13056, n = t / 40, k = t % 40;
        w[i] = f2bf(k < 32 ? vw1[n * 32 + k] * (1.f / 3.f) : 0.f);
    } else if (i < 15616) {                           // V2 [32][40]
        int t = i - 14336, n = t / 40, k = t % 40;
        w[i] = f2bf(k < 32 ? vw2[n * 32 + k] : 0.f);
    } else if (i < 18944) {                           // R1 [32][104]
        int t = i - 15616, n = t / 104, k = t % 104;
        w[i] = f2bf(k < 96 ? rw1[n * 96 + k] : 0.f);
    } else if (i < 19584) {                           // R2 [16][40]
        int t = i - 18944, n = t / 40, k = t % 40;
        w[i] = f2bf(k < 32 ? rw2[n * 32 + k] : 0.f);
    }
}

// WAVE-INDEPENDENT, ZERO-barrier, small-LDS kernel (R7 structure).
// R9 change vs R8: __launch_bounds__(256,2). Empirical law from R7/R8 on this
// toolchain: (256,w) caps VGPR at 256/w -- (256,8)->32, (256,4)->64 -- and this
// kernel's per-view pipeline needs ~100+ VGPRs, so both prior runs spilled
// ~14 KB/wave to scratch (R8: FETCH 365 MB, WRITE 500 MB). (256,2) -> cap 128:
// expect ~96-120 VGPR, ZERO spill, LDS-bound residency 12 blocks/CU and
// VGPR-bound 4-5 waves/EU. This finally runs the high-occupancy experiment.
// 4 waves/block, each wave owns 16 points end-to-end; 8192 blocks.
// PER-VIEW pipeline: h1_v -> h2_v -> t1_v -> x2_v -> CR += R1_v @ x2_v (v=0,1,2);
// live LDS = h1_v (2 KB) + 1.25 KB ping buffer = 3328 B/wave.
// TRANSPOSED-C: mfma(W,X) -> lane holds 4 consecutive feats of point n16.
// Per-wave LDS: B1 2048 B (h1_v [16][128B] -> x2_v [16][80B] -> r2b [16][80B])
//               B2 1280 B (h2_v -> t1_v -> r1 [16][80B])
__global__ __launch_bounds__(256, 2) void mlp_k(
    const float* __restrict__ feat, const ushort* __restrict__ w,
    const float* __restrict__ bb1, const float* __restrict__ bb2,
    const float* __restrict__ vb1, const float* __restrict__ vb2,
    const float* __restrict__ rb1, const float* __restrict__ rb2,
    const float* __restrict__ rw3, const float* __restrict__ rb3,
    float* __restrict__ out)
{
    __shared__ __align__(16) char sh[4][3328];        // 13312 B / block

    const int tid  = threadIdx.x;
    const int wave = tid >> 6;
    const int lane = tid & 63;
    const int n16  = lane & 15;         // point within wave tile
    const int quad = lane >> 4;         // k-chunk / feature-quad
    char* const B1 = sh[wave];          // 2048 B
    char* const B2 = sh[wave] + 2048;   // 1280 B
    const int sw7 = n16 & 7;            // swizzle for 128B rows (8 slots)
    const int sw3 = n16 & 3;            // swizzle for 80B rows (4 slots)

    const long long pbase = (long long)blockIdx.x * 64 + wave * 16;
    const long long pt    = pbase + n16;
    const float* row = feat + pt * 105;

    const ushort* WG = w;
    const ushort* WF = w + 6144;
    const ushort* W2 = w + 10752;
    const ushort* V1 = w + 13056;
    const ushort* V2 = w + 14336;
    const ushort* R1 = w + 15616;
    const ushort* R2 = w + 18944;

    // ---- rgb_in passthrough (fp32 exact): 16 pts x 9 per wave, coalesced store ----
    {
        float* o1 = out + pbase * 9;
        const float* f0 = feat + pbase * 105;
#pragma unroll
        for (int t = 0; t < 3; ++t) {
            int i = lane + t * 64;
            if (t < 2 || lane < 16) {
                int p = i / 9, r = i - p * 9, v = r / 3, c = r - v * 3;
                o1[i] = f0[p * 105 + v * 35 + c];
            }
        }
    }

    // ---- build X in registers (R6-validated): lane loads its own B-frag floats ----
    float A0[8], A1[8], A2[8];
    load8(row + 8 * quad,      A0);     // view 0, feats 8q..8q+7
    load8(row + 35 + 8 * quad, A1);     // view 1
    load8(row + 70 + 8 * quad, A2);     // view 2 (max idx 101 < 105)
    float E0[8] = {0,0,0,0,0,0,0,0}, E1[8] = {0,0,0,0,0,0,0,0}, E2[8] = {0,0,0,0,0,0,0,0};
    if (quad == 0) {                    // feats 32..39 (35..39 garbage x zero weight)
        load8(row + 32, E0);
        load8(row + 67, E1);
        if (pt == (long long)NPTS - 1) {   // guard: row+102+7 runs off the array
            E2[0] = row[102]; E2[1] = row[103]; E2[2] = row[104];
        } else {
            load8(row + 102, E2);
        }
    }
    float M[8], Vv[8], M4[8], V4[8];
#pragma unroll
    for (int j = 0; j < 8; ++j) {
        float a = A0[j], b = A1[j], c = A2[j];
        float m = (a + b + c) * (1.f / 3.f);
        float da = a - m, db = b - m, dc = c - m;
        M[j] = m; Vv[j] = (da * da + db * db + dc * dc) * (1.f / 3.f);
        float a4 = E0[j], b4 = E1[j], c4 = E2[j];
        float m4 = (a4 + b4 + c4) * (1.f / 3.f);
        float e4 = a4 - m4, f4 = b4 - m4, g4 = c4 - m4;
        M4[j] = m4; V4[j] = (e4 * e4 + f4 * f4 + g4 * g4) * (1.f / 3.f);
    }
    uint vPK[4], v4PK[4], m4PK[4];
#pragma unroll
    for (int i = 0; i < 4; ++i) {
        vPK[i]  = pack2(Vv[2 * i], Vv[2 * i + 1]);
        v4PK[i] = pack2(V4[2 * i], V4[2 * i + 1]);
        m4PK[i] = pack2(M4[2 * i], M4[2 * i + 1]);
    }
    bf16x8 XAv[3], XBv[3];
    XAv[0] = pk8(A0); XAv[1] = pk8(A1); XAv[2] = pk8(A2);
    const bf16x8 ZF = pk4u(0u, 0u, 0u, 0u);
    XBv[0] = ZF; XBv[1] = ZF; XBv[2] = ZF;
    if (quad == 0) { XBv[0] = pk8(E0); XBv[1] = pk8(E1); XBv[2] = pk8(E2); }
    const bf16x8 G0 = pk8(M);
    const int prevAddr = ((lane + 48) & 63) * 4;   // cyclic previous quad, same n16
    uint G1u[4], G2u[4];
#pragma unroll
    for (int i = 0; i < 4; ++i) {
        uint bv  = (uint)__builtin_amdgcn_ds_bpermute(prevAddr, (int)vPK[i]);
        uint bv4 = (uint)__builtin_amdgcn_ds_bpermute(prevAddr, (int)v4PK[i]);
        G1u[i] = (quad == 0) ? m4PK[i] : bv;
        G2u[i] = (quad == 0) ? bv : ((quad == 1) ? bv4 : 0u);
    }
    const bf16x8 G1 = pk4u(G1u[0], G1u[1], G1u[2], G1u[3]);
    const bf16x8 G2 = pk4u(G2u[0], G2u[1], G2u[2], G2u[3]);

    const f32x4 Z = {0.f, 0.f, 0.f, 0.f};

    // ---- Cg (global-feat part of layer 1), view-invariant: 12 MFMA, lives in regs ----
    f32x4 Cg[4];
#pragma unroll
    for (int ntl = 0; ntl < 4; ++ntl) {
        const ushort* WGb = WG + (ntl * 16 + n16) * 96 + quad * 8;
        f32x4 c = MFMA(ldw(WGb), G0, Z);
        c = MFMA(ldw(WGb + 32), G1, c);
        Cg[ntl] = MFMA(ldw(WGb + 64), G2, c);
    }

    // ---- per-view pipeline ----
    f32x4 CR[2] = {Z, Z};
#pragma unroll
    for (int v = 0; v < 3; ++v) {
        // layer 1 (view part folded onto Cg): h1_v -> B1 [16 rows][128 B], swz sw7
#pragma unroll
        for (int ntl = 0; ntl < 4; ++ntl) {
            const ushort* WFb = WF + (ntl * 16 + n16) * 72 + quad * 8;
            f32x4 C = MFMA(ldw(WFb), XAv[v], Cg[ntl]);
            C = MFMA(ldw(WFb + 32), XBv[v], C);
            const float4 bq = *(const float4*)(bb1 + ntl * 16 + quad * 4);
            float e0 = eluf(C[0] + bq.x), e1 = eluf(C[1] + bq.y);
            float e2 = eluf(C[2] + bq.z), e3 = eluf(C[3] + bq.w);
            uint2 u; u.x = pack2(e0, e1); u.y = pack2(e2, e3);
            int slot = (ntl * 2 + (quad >> 1)) ^ sw7;
            *(uint2*)(B1 + n16 * 128 + slot * 16 + (quad & 1) * 8) = u;
        }
        // layer 2: K=64 over h1_v -> h2_v in B2 [16][80 B], swz sw3
        const bf16x8 ha = *(const bf16x8*)(B1 + n16 * 128 + ((quad ^ sw7) * 16));
        const bf16x8 hb = *(const bf16x8*)(B1 + n16 * 128 + (((4 + quad) ^ sw7) * 16));
        float h2r[2][4];
#pragma unroll
        for (int n2 = 0; n2 < 2; ++n2) {
            const ushort* W2b = W2 + (n2 * 16 + n16) * 72 + quad * 8;
            f32x4 C = MFMA(ldw(W2b), ha, Z);
            C = MFMA(ldw(W2b + 32), hb, C);
            const float4 bq = *(const float4*)(bb2 + n2 * 16 + quad * 4);
            float e0 = eluf(C[0] + bq.x), e1 = eluf(C[1] + bq.y);
            float e2 = eluf(C[2] + bq.z), e3 = eluf(C[3] + bq.w);
            h2r[n2][0] = e0; h2r[n2][1] = e1; h2r[n2][2] = e2; h2r[n2][3] = e3;
            uint2 u; u.x = pack2(e0, e1); u.y = pack2(e2, e3);
            int slot = (n2 * 2 + (quad >> 1)) ^ sw3;
            *(uint2*)(B2 + n16 * 80 + slot * 16 + (quad & 1) * 8) = u;
        }
        // vis layer 1: t1_v = elu(V1 @ h2_v) -> overwrite B2 (read precedes writes)
        {
            const bf16x8 hf = *(const bf16x8*)(B2 + n16 * 80 + ((quad ^ sw3) * 16));
#pragma unroll
            for (int n2 = 0; n2 < 2; ++n2) {
                f32x4 C = MFMA(ldw(V1 + (n2 * 16 + n16) * 40 + quad * 8), hf, Z);
                const float4 bq = *(const float4*)(vb1 + n2 * 16 + quad * 4);
                float e0 = eluf(C[0] + bq.x), e1 = eluf(C[1] + bq.y);
                float e2 = eluf(C[2] + bq.z), e3 = eluf(C[3] + bq.w);
                uint2 u; u.x = pack2(e0, e1); u.y = pack2(e2, e3);
                int slot = (n2 * 2 + (quad >> 1)) ^ sw3;
                *(uint2*)(B2 + n16 * 80 + slot * 16 + (quad & 1) * 8) = u;
            }
        }
        // vis layer 2 + residual: x2_v = h2_v + elu(V2 @ t1_v) -> B1 [16][80 B]
        {
            const bf16x8 tf = *(const bf16x8*)(B2 + n16 * 80 + ((quad ^ sw3) * 16));
#pragma unroll
            for (int n2 = 0; n2 < 2; ++n2) {
                f32x4 C = MFMA(ldw(V2 + (n2 * 16 + n16) * 40 + quad * 8), tf, Z);
                const float4 bq = *(const float4*)(vb2 + n2 * 16 + quad * 4);
                float x0 = h2r[n2][0] + eluf(C[0] + bq.x);
                float x1 = h2r[n2][1] + eluf(C[1] + bq.y);
                float x2v = h2r[n2][2] + eluf(C[2] + bq.z);
                float x3 = h2r[n2][3] + eluf(C[3] + bq.w);
                uint2 u; u.x = pack2(x0, x1); u.y = pack2(x2v, x3);
                int slot = (n2 * 2 + (quad >> 1)) ^ sw3;
                *(uint2*)(B1 + n16 * 80 + slot * 16 + (quad & 1) * 8) = u;
            }
        }
        // r1 accumulation: CR += R1[:, 32v..32v+31] @ x2_v
        {
            const bf16x8 xf = *(const bf16x8*)(B1 + n16 * 80 + ((quad ^ sw3) * 16));
#pragma unroll
            for (int n2 = 0; n2 < 2; ++n2)
                CR[n2] = MFMA(ldw(R1 + (n2 * 16 + n16) * 104 + v * 32 + quad * 8), xf, CR[n2]);
        }
    }

    // ---- r1 epilogue -> B2 ----
#pragma unroll
    for (int n2 = 0; n2 < 2; ++n2) {
        const float4 bq = *(const float4*)(rb1 + n2 * 16 + quad * 4);
        float e0 = eluf(CR[n2][0] + bq.x), e1 = eluf(CR[n2][1] + bq.y);
        float e2 = eluf(CR[n2][2] + bq.z), e3 = eluf(CR[n2][3] + bq.w);
        uint2 u; u.x = pack2(e0, e1); u.y = pack2(e2, e3);
        int slot = (n2 * 2 + (quad >> 1)) ^ sw3;
        *(uint2*)(B2 + n16 * 80 + slot * 16 + (quad & 1) * 8) = u;
    }

    // ---- r2 = elu(R2 @ r1) -> fp32 B1 [16][80 B] ----
    {
        const bf16x8 rf = *(const bf16x8*)(B2 + n16 * 80 + ((quad ^ sw3) * 16));
        f32x4 C3 = MFMA(ldw(R2 + n16 * 40 + quad * 8), rf, Z);
        const float4 bq2 = *(const float4*)(rb2 + quad * 4);
        float4 rv;
        rv.x = eluf(C3[0] + bq2.x);
        rv.y = eluf(C3[1] + bq2.y);
        rv.z = eluf(C3[2] + bq2.z);
        rv.w = eluf(C3[3] + bq2.w);
        *(float4*)(B1 + n16 * 80 + quad * 16) = rv;
    }

    // ---- final 16 -> 3 + sigmoid, coalesced 192-B store per wave ----
    if (lane < 48) {
        int p = lane / 3, c = lane - p * 3;
        const float4* rr = (const float4*)(B1 + p * 80);
        const float4* w3 = (const float4*)(rw3 + c * 16);
        float4 a0 = rr[0], a1 = rr[1], a2 = rr[2], a3 = rr[3];
        float4 q0 = w3[0], q1 = w3[1], q2 = w3[2], q3 = w3[3];
        float s = rb3[c];
        s += a0.x * q0.x + a0.y * q0.y + a0.z * q0.z + a0.w * q0.w;
        s += a1.x * q1.x + a1.y * q1.y + a1.z * q1.z + a1.w * q1.w;
        s += a2.x * q2.x + a2.y * q2.y + a2.z * q2.z + a2.w * q2.w;
        s += a3.x * q3.x + a3.y * q3.y + a3.z * q3.z + a3.w * q3.w;
        out[OUT2_BASE + pbase * 3 + lane] = sigm(s);
    }
}

extern "C" void kernel_launch(void* const* d_in, const int* in_sizes, int n_in,
                              void* d_out, int out_size, void* d_ws, size_t ws_size,
                              hipStream_t stream) {
    const float* feat = (const float*)d_in[0];
    const float* bw1  = (const float*)d_in[1];
    const float* bb1  = (const float*)d_in[2];
    const float* bw2  = (const float*)d_in[3];
    const float* bb2  = (const float*)d_in[4];
    const float* vw1  = (const float*)d_in[5];
    const float* vb1  = (const float*)d_in[6];
    const float* vw2  = (const float*)d_in[7];
    const float* vb2  = (const float*)d_in[8];
    const float* rw1  = (const float*)d_in[9];
    const float* rb1  = (const float*)d_in[10];
    const float* rw2  = (const float*)d_in[11];
    const float* rb2  = (const float*)d_in[12];
    const float* rw3  = (const float*)d_in[13];
    const float* rb3  = (const float*)d_in[14];
    ushort* w  = (ushort*)d_ws;
    float* out = (float*)d_out;

    hipLaunchKernelGGL(prep_k, dim3(77), dim3(256), 0, stream,
                       bw1, bw2, vw1, vw2, rw1, rw2, w);
    hipLaunchKernelGGL(mlp_k, dim3(NBLK64), dim3(256), 0, stream,
                       feat, w, bb1, bb2, vb1, vb2, rb1, rb2, rw3, rb3, out);
}

// Round 10
// 490.638 us; speedup vs baseline: 2.3414x; 1.0039x over previous
//
#include <hip/hip_runtime.h>
#include <hip/hip_bf16.h>

// Problem constants (R=4096, S=128, V=3, F=35)
#define NPTS      524288            // R*S
#define OUT2_BASE 4718592           // NPTS*9  (rgb_in elements)
#define NBLK64    8192              // NPTS/64

using bf16x8 = __attribute__((ext_vector_type(8))) short;   // MFMA A/B frag
using f32x4  = __attribute__((ext_vector_type(4))) float;   // MFMA C/D frag

#define MFMA(a, b, c) __builtin_amdgcn_mfma_f32_16x16x32_bf16(a, b, c, 0, 0, 0)

// Weight workspace (ushort/bf16 in d_ws), [N][K] row-major, K padded, pads ZEROED:
//   WG [64][96]  @ 0      = bw1 mean part at cols 0..34, VAR part at cols 40..74
//   WF [64][72]  @ 6144   = bw1[:, 70:105](view part),  cols 35..71 = 0
//   W2 [32][72]  @ 10752  = bw2,  cols 64..71 = 0
//   V1 [32][40]  @ 13056  = vw1/3 (x/num_views folded), cols 32..39 = 0
//   V2 [32][40]  @ 14336  = vw2,  cols 32..39 = 0
//   R1 [32][104] @ 15616  = rw1,  cols 96..103 = 0
//   R2 [16][40]  @ 18944  = rw2,  cols 32..39 = 0

__device__ __forceinline__ ushort f2bf(float f) {
    union { float f; unsigned u; } v; v.f = f;
    unsigned u = v.u;
    unsigned r = u + 0x7fffu + ((u >> 16) & 1u);   // RTNE
    return (ushort)(r >> 16);
}
__device__ __forceinline__ uint pack2(float a, float b) {   // lo=bf16(a), hi=bf16(b)
    union { __hip_bfloat162 h; uint u; } cv;
    cv.h = __float22bfloat162_rn(make_float2(a, b));
    return cv.u;
}
__device__ __forceinline__ float eluf(float x) {
    return fmaxf(x, 0.f) + __expf(fminf(x, 0.f)) - 1.f;
}
__device__ __forceinline__ float sigm(float x) { return 1.f / (1.f + __expf(-x)); }

__device__ __forceinline__ void load8(const float* __restrict__ p, float* d) {
    __builtin_memcpy(d, p, 16);
    __builtin_memcpy(d + 4, p + 4, 16);
}
__device__ __forceinline__ bf16x8 pk8(const float* x) {     // 8 f32 -> bf16x8
    union { uint4 u; bf16x8 h; } cv;
    cv.u = make_uint4(pack2(x[0], x[1]), pack2(x[2], x[3]),
                      pack2(x[4], x[5]), pack2(x[6], x[7]));
    return cv.h;
}
__device__ __forceinline__ bf16x8 pk4u(uint a, uint b, uint c, uint d) {
    union { uint4 u; bf16x8 h; } cv;
    cv.u = make_uint4(a, b, c, d);
    return cv.h;
}
__device__ __forceinline__ bf16x8 ldw(const ushort* p) { return *(const bf16x8*)p; }

__global__ void prep_k(const float* __restrict__ bw1, const float* __restrict__ bw2,
                       const float* __restrict__ vw1, const float* __restrict__ vw2,
                       const float* __restrict__ rw1, const float* __restrict__ rw2,
                       ushort* __restrict__ w)
{
    int i = blockIdx.x * 256 + threadIdx.x;
    if (i < 6144) {                                   // WG [64][96] mean@0..34, var@40..74
        int n = i / 96, k = i % 96;
        float val = 0.f;
        if (k < 35)                 val = bw1[n * 105 + k];
        else if (k >= 40 && k < 75) val = bw1[n * 105 + 35 + (k - 40)];
        w[i] = f2bf(val);
    } else if (i < 10752) {                           // WF [64][72]
        int t = i - 6144, n = t / 72, k = t % 72;
        w[i] = f2bf(k < 35 ? bw1[n * 105 + 70 + k] : 0.f);
    } else if (i < 13056) {                           // W2 [32][72]
        int t = i - 10752, n = t / 72, k = t % 72;
        w[i] = f2bf(k < 64 ? bw2[n * 64 + k] : 0.f);
    } else if (i < 14336) {                           // V1 [32][40] (/3 folded)
        int t = i - 13056, n = t / 40, k = t % 40;
        w[i] = f2bf(k < 32 ? vw1[n * 32 + k] * (1.f / 3.f) : 0.f);
    } else if (i < 15616) {                           // V2 [32][40]
        int t = i - 14336, n = t / 40, k = t % 40;
        w[i] = f2bf(k < 32 ? vw2[n * 32 + k] : 0.f);
    } else if (i < 18944) {                           // R1 [32][104]
        int t = i - 15616, n = t / 104, k = t % 104;
        w[i] = f2bf(k < 96 ? rw1[n * 96 + k] : 0.f);
    } else if (i < 19584) {                           // R2 [16][40]
        int t = i - 18944, n = t / 40, k = t % 40;
        w[i] = f2bf(k < 32 ? rw2[n * 32 + k] : 0.f);
    }
}

// WAVE-INDEPENDENT, ZERO-barrier, small-LDS kernel (R7 structure).
// R10 change vs R9: __launch_bounds__(256) -- NO waves-per-EU arg. Empirical law
// from R7/R8/R9 on this toolchain: (256,w) pins residency to w blocks/CU
// (w=8->89% occ, w=4->45%, w=2->22%) AND caps VGPR at 256/w (32/64/128). This
// kernel needs ~88 VGPR, so every w>=3 spills and w=2 strangles residency.
// With no wave constraint: natural VGPR ~88 -> 512/88 = 5 waves/SIMD, LDS
// 13312 B -> 12 blocks/CU possible => hardware residency ~5 blocks = 20
// waves/CU (62%), the highest non-spilled occupancy yet.
// 4 waves/block, each wave owns 16 points end-to-end; 8192 blocks.
// PER-VIEW pipeline: h1_v -> h2_v -> t1_v -> x2_v -> CR += R1_v @ x2_v (v=0,1,2);
// live LDS = h1_v (2 KB) + 1.25 KB ping buffer = 3328 B/wave.
// TRANSPOSED-C: mfma(W,X) -> lane holds 4 consecutive feats of point n16.
// Per-wave LDS: B1 2048 B (h1_v [16][128B] -> x2_v [16][80B] -> r2b [16][80B])
//               B2 1280 B (h2_v -> t1_v -> r1 [16][80B])
__global__ __launch_bounds__(256) void mlp_k(
    const float* __restrict__ feat, const ushort* __restrict__ w,
    const float* __restrict__ bb1, const float* __restrict__ bb2,
    const float* __restrict__ vb1, const float* __restrict__ vb2,
    const float* __restrict__ rb1, const float* __restrict__ rb2,
    const float* __restrict__ rw3, const float* __restrict__ rb3,
    float* __restrict__ out)
{
    __shared__ __align__(16) char sh[4][3328];        // 13312 B / block

    const int tid  = threadIdx.x;
    const int wave = tid >> 6;
    const int lane = tid & 63;
    const int n16  = lane & 15;         // point within wave tile
    const int quad = lane >> 4;         // k-chunk / feature-quad
    char* const B1 = sh[wave];          // 2048 B
    char* const B2 = sh[wave] + 2048;   // 1280 B
    const int sw7 = n16 & 7;            // swizzle for 128B rows (8 slots)
    const int sw3 = n16 & 3;            // swizzle for 80B rows (4 slots)

    const long long pbase = (long long)blockIdx.x * 64 + wave * 16;
    const long long pt    = pbase + n16;
    const float* row = feat + pt * 105;

    const ushort* WG = w;
    const ushort* WF = w + 6144;
    const ushort* W2 = w + 10752;
    const ushort* V1 = w + 13056;
    const ushort* V2 = w + 14336;
    const ushort* R1 = w + 15616;
    const ushort* R2 = w + 18944;

    // ---- rgb_in passthrough (fp32 exact): 16 pts x 9 per wave, coalesced store ----
    {
        float* o1 = out + pbase * 9;
        const float* f0 = feat + pbase * 105;
#pragma unroll
        for (int t = 0; t < 3; ++t) {
            int i = lane + t * 64;
            if (t < 2 || lane < 16) {
                int p = i / 9, r = i - p * 9, v = r / 3, c = r - v * 3;
                o1[i] = f0[p * 105 + v * 35 + c];
            }
        }
    }

    // ---- build X in registers (R6-validated): lane loads its own B-frag floats ----
    float A0[8], A1[8], A2[8];
    load8(row + 8 * quad,      A0);     // view 0, feats 8q..8q+7
    load8(row + 35 + 8 * quad, A1);     // view 1
    load8(row + 70 + 8 * quad, A2);     // view 2 (max idx 101 < 105)
    float E0[8] = {0,0,0,0,0,0,0,0}, E1[8] = {0,0,0,0,0,0,0,0}, E2[8] = {0,0,0,0,0,0,0,0};
    if (quad == 0) {                    // feats 32..39 (35..39 garbage x zero weight)
        load8(row + 32, E0);
        load8(row + 67, E1);
        if (pt == (long long)NPTS - 1) {   // guard: row+102+7 runs off the array
            E2[0] = row[102]; E2[1] = row[103]; E2[2] = row[104];
        } else {
            load8(row + 102, E2);
        }
    }
    float M[8], Vv[8], M4[8], V4[8];
#pragma unroll
    for (int j = 0; j < 8; ++j) {
        float a = A0[j], b = A1[j], c = A2[j];
        float m = (a + b + c) * (1.f / 3.f);
        float da = a - m, db = b - m, dc = c - m;
        M[j] = m; Vv[j] = (da * da + db * db + dc * dc) * (1.f / 3.f);
        float a4 = E0[j], b4 = E1[j], c4 = E2[j];
        float m4 = (a4 + b4 + c4) * (1.f / 3.f);
        float e4 = a4 - m4, f4 = b4 - m4, g4 = c4 - m4;
        M4[j] = m4; V4[j] = (e4 * e4 + f4 * f4 + g4 * g4) * (1.f / 3.f);
    }
    uint vPK[4], v4PK[4], m4PK[4];
#pragma unroll
    for (int i = 0; i < 4; ++i) {
        vPK[i]  = pack2(Vv[2 * i], Vv[2 * i + 1]);
        v4PK[i] = pack2(V4[2 * i], V4[2 * i + 1]);
        m4PK[i] = pack2(M4[2 * i], M4[2 * i + 1]);
    }
    bf16x8 XAv[3], XBv[3];
    XAv[0] = pk8(A0); XAv[1] = pk8(A1); XAv[2] = pk8(A2);
    const bf16x8 ZF = pk4u(0u, 0u, 0u, 0u);
    XBv[0] = ZF; XBv[1] = ZF; XBv[2] = ZF;
    if (quad == 0) { XBv[0] = pk8(E0); XBv[1] = pk8(E1); XBv[2] = pk8(E2); }
    const bf16x8 G0 = pk8(M);
    const int prevAddr = ((lane + 48) & 63) * 4;   // cyclic previous quad, same n16
    uint G1u[4], G2u[4];
#pragma unroll
    for (int i = 0; i < 4; ++i) {
        uint bv  = (uint)__builtin_amdgcn_ds_bpermute(prevAddr, (int)vPK[i]);
        uint bv4 = (uint)__builtin_amdgcn_ds_bpermute(prevAddr, (int)v4PK[i]);
        G1u[i] = (quad == 0) ? m4PK[i] : bv;
        G2u[i] = (quad == 0) ? bv : ((quad == 1) ? bv4 : 0u);
    }
    const bf16x8 G1 = pk4u(G1u[0], G1u[1], G1u[2], G1u[3]);
    const bf16x8 G2 = pk4u(G2u[0], G2u[1], G2u[2], G2u[3]);

    const f32x4 Z = {0.f, 0.f, 0.f, 0.f};

    // ---- Cg (global-feat part of layer 1), view-invariant: 12 MFMA, lives in regs ----
    f32x4 Cg[4];
#pragma unroll
    for (int ntl = 0; ntl < 4; ++ntl) {
        const ushort* WGb = WG + (ntl * 16 + n16) * 96 + quad * 8;
        f32x4 c = MFMA(ldw(WGb), G0, Z);
        c = MFMA(ldw(WGb + 32), G1, c);
        Cg[ntl] = MFMA(ldw(WGb + 64), G2, c);
    }

    // ---- per-view pipeline ----
    f32x4 CR[2] = {Z, Z};
#pragma unroll
    for (int v = 0; v < 3; ++v) {
        // layer 1 (view part folded onto Cg): h1_v -> B1 [16 rows][128 B], swz sw7
#pragma unroll
        for (int ntl = 0; ntl < 4; ++ntl) {
            const ushort* WFb = WF + (ntl * 16 + n16) * 72 + quad * 8;
            f32x4 C = MFMA(ldw(WFb), XAv[v], Cg[ntl]);
            C = MFMA(ldw(WFb + 32), XBv[v], C);
            const float4 bq = *(const float4*)(bb1 + ntl * 16 + quad * 4);
            float e0 = eluf(C[0] + bq.x), e1 = eluf(C[1] + bq.y);
            float e2 = eluf(C[2] + bq.z), e3 = eluf(C[3] + bq.w);
            uint2 u; u.x = pack2(e0, e1); u.y = pack2(e2, e3);
            int slot = (ntl * 2 + (quad >> 1)) ^ sw7;
            *(uint2*)(B1 + n16 * 128 + slot * 16 + (quad & 1) * 8) = u;
        }
        // layer 2: K=64 over h1_v -> h2_v in B2 [16][80 B], swz sw3
        const bf16x8 ha = *(const bf16x8*)(B1 + n16 * 128 + ((quad ^ sw7) * 16));
        const bf16x8 hb = *(const bf16x8*)(B1 + n16 * 128 + (((4 + quad) ^ sw7) * 16));
        float h2r[2][4];
#pragma unroll
        for (int n2 = 0; n2 < 2; ++n2) {
            const ushort* W2b = W2 + (n2 * 16 + n16) * 72 + quad * 8;
            f32x4 C = MFMA(ldw(W2b), ha, Z);
            C = MFMA(ldw(W2b + 32), hb, C);
            const float4 bq = *(const float4*)(bb2 + n2 * 16 + quad * 4);
            float e0 = eluf(C[0] + bq.x), e1 = eluf(C[1] + bq.y);
            float e2 = eluf(C[2] + bq.z), e3 = eluf(C[3] + bq.w);
            h2r[n2][0] = e0; h2r[n2][1] = e1; h2r[n2][2] = e2; h2r[n2][3] = e3;
            uint2 u; u.x = pack2(e0, e1); u.y = pack2(e2, e3);
            int slot = (n2 * 2 + (quad >> 1)) ^ sw3;
            *(uint2*)(B2 + n16 * 80 + slot * 16 + (quad & 1) * 8) = u;
        }
        // vis layer 1: t1_v = elu(V1 @ h2_v) -> overwrite B2 (read precedes writes)
        {
            const bf16x8 hf = *(const bf16x8*)(B2 + n16 * 80 + ((quad ^ sw3) * 16));
#pragma unroll
            for (int n2 = 0; n2 < 2; ++n2) {
                f32x4 C = MFMA(ldw(V1 + (n2 * 16 + n16) * 40 + quad * 8), hf, Z);
                const float4 bq = *(const float4*)(vb1 + n2 * 16 + quad * 4);
                float e0 = eluf(C[0] + bq.x), e1 = eluf(C[1] + bq.y);
                float e2 = eluf(C[2] + bq.z), e3 = eluf(C[3] + bq.w);
                uint2 u; u.x = pack2(e0, e1); u.y = pack2(e2, e3);
                int slot = (n2 * 2 + (quad >> 1)) ^ sw3;
                *(uint2*)(B2 + n16 * 80 + slot * 16 + (quad & 1) * 8) = u;
            }
        }
        // vis layer 2 + residual: x2_v = h2_v + elu(V2 @ t1_v) -> B1 [16][80 B]
        {
            const bf16x8 tf = *(const bf16x8*)(B2 + n16 * 80 + ((quad ^ sw3) * 16));
#pragma unroll
            for (int n2 = 0; n2 < 2; ++n2) {
                f32x4 C = MFMA(ldw(V2 + (n2 * 16 + n16) * 40 + quad * 8), tf, Z);
                const float4 bq = *(const float4*)(vb2 + n2 * 16 + quad * 4);
                float x0 = h2r[n2][0] + eluf(C[0] + bq.x);
                float x1 = h2r[n2][1] + eluf(C[1] + bq.y);
                float x2v = h2r[n2][2] + eluf(C[2] + bq.z);
                float x3 = h2r[n2][3] + eluf(C[3] + bq.w);
                uint2 u; u.x = pack2(x0, x1); u.y = pack2(x2v, x3);
                int slot = (n2 * 2 + (quad >> 1)) ^ sw3;
                *(uint2*)(B1 + n16 * 80 + slot * 16 + (quad & 1) * 8) = u;
            }
        }
        // r1 accumulation: CR += R1[:, 32v..32v+31] @ x2_v
        {
            const bf16x8 xf = *(const bf16x8*)(B1 + n16 * 80 + ((quad ^ sw3) * 16));
#pragma unroll
            for (int n2 = 0; n2 < 2; ++n2)
                CR[n2] = MFMA(ldw(R1 + (n2 * 16 + n16) * 104 + v * 32 + quad * 8), xf, CR[n2]);
        }
    }

    // ---- r1 epilogue -> B2 ----
#pragma unroll
    for (int n2 = 0; n2 < 2; ++n2) {
        const float4 bq = *(const float4*)(rb1 + n2 * 16 + quad * 4);
        float e0 = eluf(CR[n2][0] + bq.x), e1 = eluf(CR[n2][1] + bq.y);
        float e2 = eluf(CR[n2][2] + bq.z), e3 = eluf(CR[n2][3] + bq.w);
        uint2 u; u.x = pack2(e0, e1); u.y = pack2(e2, e3);
        int slot = (n2 * 2 + (quad >> 1)) ^ sw3;
        *(uint2*)(B2 + n16 * 80 + slot * 16 + (quad & 1) * 8) = u;
    }

    // ---- r2 = elu(R2 @ r1) -> fp32 B1 [16][80 B] ----
    {
        const bf16x8 rf = *(const bf16x8*)(B2 + n16 * 80 + ((quad ^ sw3) * 16));
        f32x4 C3 = MFMA(ldw(R2 + n16 * 40 + quad * 8), rf, Z);
        const float4 bq2 = *(const float4*)(rb2 + quad * 4);
        float4 rv;
        rv.x = eluf(C3[0] + bq2.x);
        rv.y = eluf(C3[1] + bq2.y);
        rv.z = eluf(C3[2] + bq2.z);
        rv.w = eluf(C3[3] + bq2.w);
        *(float4*)(B1 + n16 * 80 + quad * 16) = rv;
    }

    // ---- final 16 -> 3 + sigmoid, coalesced 192-B store per wave ----
    if (lane < 48) {
        int p = lane / 3, c = lane - p * 3;
        const float4* rr = (const float4*)(B1 + p * 80);
        const float4* w3 = (const float4*)(rw3 + c * 16);
        float4 a0 = rr[0], a1 = rr[1], a2 = rr[2], a3 = rr[3];
        float4 q0 = w3[0], q1 = w3[1], q2 = w3[2], q3 = w3[3];
        float s = rb3[c];
        s += a0.x * q0.x + a0.y * q0.y + a0.z * q0.z + a0.w * q0.w;
        s += a1.x * q1.x + a1.y * q1.y + a1.z * q1.z + a1.w * q1.w;
        s += a2.x * q2.x + a2.y * q2.y + a2.z * q2.z + a2.w * q2.w;
        s += a3.x * q3.x + a3.y * q3.y + a3.z * q3.z + a3.w * q3.w;
        out[OUT2_BASE + pbase * 3 + lane] = sigm(s);
    }
}

extern "C" void kernel_launch(void* const* d_in, const int* in_sizes, int n_in,
                              void* d_out, int out_size, void* d_ws, size_t ws_size,
                              hipStream_t stream) {
    const float* feat = (const float*)d_in[0];
    const float* bw1  = (const float*)d_in[1];
    const float* bb1  = (const float*)d_in[2];
    const float* bw2  = (const float*)d_in[3];
    const float* bb2  = (const float*)d_in[4];
    const float* vw1  = (const float*)d_in[5];
    const float* vb1  = (const float*)d_in[6];
    const float* vw2  = (const float*)d_in[7];
    const float* vb2  = (const float*)d_in[8];
    const float* rw1  = (const float*)d_in[9];
    const float* rb1  = (const float*)d_in[10];
    const float* rw2  = (const float*)d_in[11];
    const float* rb2  = (const float*)d_in[12];
    const float* rw3  = (const float*)d_in[13];
    const float* rb3  = (const float*)d_in[14];
    ushort* w  = (ushort*)d_ws;
    float* out = (float*)d_out;

    hipLaunchKernelGGL(prep_k, dim3(77), dim3(256), 0, stream,
                       bw1, bw2, vw1, vw2, rw1, rw2, w);
    hipLaunchKernelGGL(mlp_k, dim3(NBLK64), dim3(256), 0, stream,
                       feat, w, bb1, bb2, vb1, vb2, rb1, rb2, rw3, rb3, out);
}